// Round 6
// baseline (753.220 us; speedup 1.0000x reference)
//
#include <hip/hip_runtime.h>
#include <cmath>

static inline int cdiv(long a, int b){ return (int)((a + b - 1) / b); }

__device__ __forceinline__ float lrelu(float x){ return x > 0.f ? x : 0.2f * x; }
__device__ __forceinline__ float elu1(float x){ return x > 0.f ? x : expm1f(x); }

// compiler-level fence: keep LDS writes (phase1) before LDS reads (phase2)
// within the same wave; HW DS pipe is in-order per wave.
#define WAVE_FENCE() do { asm volatile("" ::: "memory"); __builtin_amdgcn_sched_barrier(0); } while(0)

#define W_SHIFT 7                 // 128 nodes per bucket
#define NBMAX   1024              // LDS histogram size (>= nb)
#define EID_BITS 22               // E < 2^22
#define EID_MASK ((1 << EID_BITS) - 1)

// ---------------- CSR build (two-level binned scatter) ----------------

__global__ void hist2_kernel(const int* __restrict__ ei, int E,
                             int* __restrict__ cnt, int* __restrict__ bcnt){
  __shared__ int s_b[NBMAX];
  for (int i = threadIdx.x; i < NBMAX; i += blockDim.x) s_b[i] = 0;
  __syncthreads();
  int stride = gridDim.x * blockDim.x;
  for (int e = blockIdx.x * blockDim.x + threadIdx.x; e < E; e += stride){
    int d = ei[E + e];
    atomicAdd(&cnt[d], 1);
    atomicAdd(&s_b[d >> W_SHIFT], 1);
  }
  __syncthreads();
  for (int i = threadIdx.x; i < NBMAX; i += blockDim.x)
    if (s_b[i]) atomicAdd(&bcnt[i], s_b[i]);
}

#define SCAN_B 1024
__global__ void scan_partial_kernel(const int* __restrict__ cnt, int* __restrict__ row_start,
                                    int* __restrict__ partials, int n){
  __shared__ int s[SCAN_B];
  int t = threadIdx.x, i = blockIdx.x * SCAN_B + t;
  int v = (i < n) ? cnt[i] : 0;
  s[t] = v; __syncthreads();
  #pragma unroll
  for (int off = 1; off < SCAN_B; off <<= 1){
    int u = (t >= off) ? s[t - off] : 0;
    __syncthreads();
    s[t] += u;
    __syncthreads();
  }
  if (i < n) row_start[i] = s[t] - v;
  if (t == SCAN_B - 1) partials[blockIdx.x] = s[t];
}

__global__ void scan_tops_kernel(int* __restrict__ partials, int nb,
                                 int* __restrict__ row_start, int n, int total){
  __shared__ int s[256];
  int t = threadIdx.x;
  int v = (t < nb) ? partials[t] : 0;
  s[t] = v; __syncthreads();
  #pragma unroll
  for (int off = 1; off < 256; off <<= 1){
    int u = (t >= off) ? s[t - off] : 0;
    __syncthreads();
    s[t] += u;
    __syncthreads();
  }
  if (t < nb) partials[t] = s[t] - v;
  if (t == 0) row_start[n] = total;
}

__global__ void scan_add_kernel(const int* __restrict__ partials, int* __restrict__ row_start, int n){
  int i = blockIdx.x * blockDim.x + threadIdx.x;
  if (i < n) row_start[i] += partials[i >> 10];
}

__global__ void scan_buckets_kernel(const int* __restrict__ bcnt, int nb, int total,
                                    int* __restrict__ bstart, int* __restrict__ bcursor){
  __shared__ int s[1024];
  int t = threadIdx.x;
  int v = (t < nb) ? bcnt[t] : 0;
  s[t] = v; __syncthreads();
  #pragma unroll
  for (int off = 1; off < 1024; off <<= 1){
    int u = (t >= off) ? s[t - off] : 0;
    __syncthreads();
    s[t] += u;
    __syncthreads();
  }
  if (t < nb){ bstart[t] = s[t] - v; bcursor[t] = s[t] - v; }
  if (t == 0) bstart[nb] = total;
}

#define S3_CHUNK 8192
// fallback variant: meta only
__global__ void multisplit_kernel(const int* __restrict__ ei, int E,
                                  int* __restrict__ bcursor, int2* __restrict__ staged){
  __shared__ int s_hist[NBMAX];
  __shared__ int s_base[NBMAX];
  int t = threadIdx.x;
  for (int i = t; i < NBMAX; i += 256) s_hist[i] = 0;
  __syncthreads();
  int lo = blockIdx.x * S3_CHUNK;
  int hi = min(lo + S3_CHUNK, E);
  for (int e = lo + t; e < hi; e += 256)
    atomicAdd(&s_hist[ei[E + e] >> W_SHIFT], 1);
  __syncthreads();
  for (int i = t; i < NBMAX; i += 256){
    int c = s_hist[i];
    s_base[i] = c ? atomicAdd(&bcursor[i], c) : 0;
    s_hist[i] = 0;
  }
  __syncthreads();
  for (int e = lo + t; e < hi; e += 256){
    int d = ei[E + e];
    int b = d >> W_SHIFT;
    int pos = s_base[b] + atomicAdd(&s_hist[b], 1);
    staged[pos] = make_int2(ei[e], e | ((d & ((1 << W_SHIFT) - 1)) << EID_BITS));
  }
}

// fast variant: stream eattr sequentially, stage precomputed edge scores
__global__ void multisplit_esc_kernel(const int* __restrict__ ei, int E,
                                      const float* __restrict__ eattr, const float* __restrict__ wev,
                                      int* __restrict__ bcursor, int2* __restrict__ staged_meta,
                                      float4* __restrict__ staged_esc){
  __shared__ int s_hist[NBMAX];
  __shared__ int s_base[NBMAX];
  __shared__ float s_wev[32];
  int t = threadIdx.x;
  if (t < 32) s_wev[t] = wev[t];
  for (int i = t; i < NBMAX; i += 256) s_hist[i] = 0;
  __syncthreads();
  int lo = blockIdx.x * S3_CHUNK;
  int hi = min(lo + S3_CHUNK, E);
  for (int e = lo + t; e < hi; e += 256)
    atomicAdd(&s_hist[ei[E + e] >> W_SHIFT], 1);
  __syncthreads();
  for (int i = t; i < NBMAX; i += 256){
    int c = s_hist[i];
    s_base[i] = c ? atomicAdd(&bcursor[i], c) : 0;
    s_hist[i] = 0;
  }
  __syncthreads();
  for (int e = lo + t; e < hi; e += 256){
    int d = ei[E + e];
    int b = d >> W_SHIFT;
    int pos = s_base[b] + atomicAdd(&s_hist[b], 1);
    const float4* ea = (const float4*)(eattr + (size_t)e * 8);
    float4 v0 = ea[0], v1 = ea[1];
    float av[8] = {v0.x, v0.y, v0.z, v0.w, v1.x, v1.y, v1.z, v1.w};
    float e0 = 0, e1 = 0, e2 = 0, e3 = 0;
    #pragma unroll
    for (int d2i = 0; d2i < 8; ++d2i){
      e0 = fmaf(av[d2i], s_wev[d2i * 4 + 0], e0);
      e1 = fmaf(av[d2i], s_wev[d2i * 4 + 1], e1);
      e2 = fmaf(av[d2i], s_wev[d2i * 4 + 2], e2);
      e3 = fmaf(av[d2i], s_wev[d2i * 4 + 3], e3);
    }
    staged_meta[pos] = make_int2(ei[e], e | ((d & ((1 << W_SHIFT) - 1)) << EID_BITS));
    staged_esc[pos] = make_float4(e0, e1, e2, e3);
  }
}

__global__ void bucket_scatter_kernel(const int* __restrict__ bstart, const int2* __restrict__ staged,
                                      const int* __restrict__ row_start, int n,
                                      int2* __restrict__ recs){
  __shared__ int s_cur[1 << W_SHIFT];
  int b = blockIdx.x, t = threadIdx.x;
  int node0 = b << W_SHIFT;
  if (t < (1 << W_SHIFT)){
    int nd = node0 + t;
    s_cur[t] = (nd < n) ? row_start[nd] : 0;
  }
  __syncthreads();
  int lo = bstart[b], hi = bstart[b + 1];
  for (int i = lo + t; i < hi; i += 256){
    int2 r = staged[i];
    int dl = (unsigned)r.y >> EID_BITS;
    int pos = atomicAdd(&s_cur[dl], 1);
    recs[pos] = make_int2(r.x, r.y & EID_MASK);
  }
}

__global__ void bucket_scatter_esc_kernel(const int* __restrict__ bstart,
                                          const int2* __restrict__ staged_meta,
                                          const float4* __restrict__ staged_esc,
                                          const int* __restrict__ row_start, int n,
                                          int2* __restrict__ recs, float4* __restrict__ esc_perm){
  __shared__ int s_cur[1 << W_SHIFT];
  int b = blockIdx.x, t = threadIdx.x;
  int node0 = b << W_SHIFT;
  if (t < (1 << W_SHIFT)){
    int nd = node0 + t;
    s_cur[t] = (nd < n) ? row_start[nd] : 0;
  }
  __syncthreads();
  int lo = bstart[b], hi = bstart[b + 1];
  for (int i = lo + t; i < hi; i += 256){
    int2 r = staged_meta[i];
    float4 es = staged_esc[i];
    int dl = (unsigned)r.y >> EID_BITS;
    int pos = atomicAdd(&s_cur[dl], 1);
    recs[pos] = make_int2(r.x, r.y & EID_MASK);
    esc_perm[pos] = es;
  }
}

// wev[d*4+h] = sum_c We1[d, h*8+c] * a_e1[h,c]
__global__ void wevec_kernel(const float* __restrict__ We, const float* __restrict__ ae,
                             float* __restrict__ wev){
  int i = threadIdx.x;
  if (i >= 32) return;
  int d = i >> 2, h = i & 3;
  float acc = 0.f;
  #pragma unroll
  for (int c = 0; c < 8; ++c) acc = fmaf(We[d * 32 + h * 8 + c], ae[h * 8 + c], acc);
  wev[d * 4 + h] = acc;
}

// ---------------- fused node transform + attention pre-scores ----------------
template<int K, int M, int C>
__global__ void gemm_score_kernel(const float* __restrict__ A, const float* __restrict__ W,
                                  const float* __restrict__ asrc, const float* __restrict__ adst,
                                  float* __restrict__ out, float* __restrict__ sS,
                                  float* __restrict__ sD, int n){
  __shared__ float Ws[K * M];
  __shared__ float s_as[M], s_ad[M];
  for (int i = threadIdx.x; i < K * M; i += blockDim.x) Ws[i] = W[i];
  if (threadIdx.x < M){ s_as[threadIdx.x] = asrc[threadIdx.x]; s_ad[threadIdx.x] = adst[threadIdx.x]; }
  __syncthreads();
  constexpr int ROWS = 256 / M;
  int row = blockIdx.x * ROWS + (int)threadIdx.x / M;
  int col = (int)threadIdx.x % M;
  if (row >= n) return;
  const float4* a4 = (const float4*)(A + (size_t)row * K);
  float acc = 0.f;
  #pragma unroll
  for (int k4 = 0; k4 < K / 4; ++k4){
    float4 av = a4[k4];
    acc = fmaf(av.x, Ws[(k4 * 4 + 0) * M + col], acc);
    acc = fmaf(av.y, Ws[(k4 * 4 + 1) * M + col], acc);
    acc = fmaf(av.z, Ws[(k4 * 4 + 2) * M + col], acc);
    acc = fmaf(av.w, Ws[(k4 * 4 + 3) * M + col], acc);
  }
  out[(size_t)row * M + col] = acc;
  float ps = acc * s_as[col], pd = acc * s_ad[col];
  #pragma unroll
  for (int off = 1; off < C; off <<= 1){
    ps += __shfl_xor(ps, off, 64);
    pd += __shfl_xor(pd, off, 64);
  }
  if ((col & (C - 1)) == 0){
    int h = col / C;
    sS[(size_t)row * 4 + h] = ps;
    sD[(size_t)row * 4 + h] = pd;
  }
}

// ---------------- CSR gather-aggregate ----------------
// MODE 0: concat heads + bias + ELU (layer1, OUT=32)
// MODE 1: mean heads + bias + ELU   (layer2, OUT=32)
// MODE 2: mean heads + bias         (layer3, OUT=4) — fused lane-per-edge path
// EMODE 0: no edge scores; 1: sequential esc_perm; 2: gather raw eattr (fallback)
template<int C, int MODE, int EMODE>
__global__ void gather_kernel(const int* __restrict__ row_start, const int2* __restrict__ recs,
                              const float* __restrict__ eattr, const float4* __restrict__ escp,
                              const float* __restrict__ wev,
                              const float* __restrict__ sS, const float* __restrict__ sD,
                              const float* __restrict__ xh, const float* __restrict__ bias,
                              float* __restrict__ out, int n){
  int wv = threadIdx.x >> 6, lane = threadIdx.x & 63;
  int node = blockIdx.x * 4 + wv;

  if constexpr (MODE == 2){
    if (node >= n) return;
    int rs = row_start[node], deg = row_start[node + 1] - rs;
    float4 sd4 = ((const float4*)sD)[node];
    float4 acc = {0,0,0,0}, dsum = {0,0,0,0};
    for (int k = lane; k < deg; k += 64){
      int s = recs[rs + k].x;
      float4 ss = ((const float4*)sS)[s];
      float4 w;
      w.x = expf(lrelu(ss.x + sd4.x)); w.y = expf(lrelu(ss.y + sd4.y));
      w.z = expf(lrelu(ss.z + sd4.z)); w.w = expf(lrelu(ss.w + sd4.w));
      dsum.x += w.x; dsum.y += w.y; dsum.z += w.z; dsum.w += w.w;
      float4 xv = ((const float4*)xh)[s];
      acc.x = fmaf(w.x, xv.x, acc.x); acc.y = fmaf(w.y, xv.y, acc.y);
      acc.z = fmaf(w.z, xv.z, acc.z); acc.w = fmaf(w.w, xv.w, acc.w);
    }
    #pragma unroll
    for (int off = 1; off < 64; off <<= 1){
      acc.x += __shfl_xor(acc.x, off, 64); acc.y += __shfl_xor(acc.y, off, 64);
      acc.z += __shfl_xor(acc.z, off, 64); acc.w += __shfl_xor(acc.w, off, 64);
      dsum.x += __shfl_xor(dsum.x, off, 64); dsum.y += __shfl_xor(dsum.y, off, 64);
      dsum.z += __shfl_xor(dsum.z, off, 64); dsum.w += __shfl_xor(dsum.w, off, 64);
    }
    if (lane == 0){
      float4 ssn = ((const float4*)sS)[node];
      float4 wsf;
      wsf.x = expf(lrelu(ssn.x + sd4.x)); wsf.y = expf(lrelu(ssn.y + sd4.y));
      wsf.z = expf(lrelu(ssn.z + sd4.z)); wsf.w = expf(lrelu(ssn.w + sd4.w));
      float4 xvn = ((const float4*)xh)[node];
      float v = (acc.x + wsf.x * xvn.x) / (dsum.x + wsf.x + 1e-16f)
              + (acc.y + wsf.y * xvn.y) / (dsum.y + wsf.y + 1e-16f)
              + (acc.z + wsf.z * xvn.z) / (dsum.z + wsf.z + 1e-16f)
              + (acc.w + wsf.w * xvn.w) / (dsum.w + wsf.w + 1e-16f);
      out[node] = 0.25f * v + bias[0];
    }
    return;
  } else {
  __shared__ float4 s_w[4][64];
  __shared__ int    s_src[4][64];
  __shared__ float  s_wev[32];
  if (EMODE == 2 && threadIdx.x < 32) s_wev[threadIdx.x] = wev[threadIdx.x];
  if (EMODE == 2) __syncthreads();
  if (node >= n) return;
  int rs = row_start[node], deg = row_start[node + 1] - rs;
  float4 sd4 = ((const float4*)sD)[node];
  int q = lane & 7;          // float4 column of the 32-wide row
  int h = q >> 1;            // head for this column group
  int sg = lane >> 3;        // slot group (8 edges per phase-2 iter)
  float d0 = 0, d1 = 0, d2 = 0, d3 = 0;
  float es0 = 0, es1 = 0, es2 = 0, es3 = 0;
  float4 acc = {0,0,0,0};

  for (int base = 0; base < deg; base += 64){
    int k = base + lane;
    float4 w = {0,0,0,0}; int s = 0;
    if (k < deg){
      int2 rec = recs[rs + k];
      s = rec.x;
      float4 ss = ((const float4*)sS)[s];
      float a0 = ss.x + sd4.x, a1 = ss.y + sd4.y, a2 = ss.z + sd4.z, a3 = ss.w + sd4.w;
      if constexpr (EMODE == 1){
        float4 e4 = escp[rs + k];
        a0 += e4.x; a1 += e4.y; a2 += e4.z; a3 += e4.w;
        es0 += e4.x; es1 += e4.y; es2 += e4.z; es3 += e4.w;
      } else if constexpr (EMODE == 2){
        const float4* ea = (const float4*)(eattr + (size_t)rec.y * 8);
        float4 v0 = ea[0], v1 = ea[1];
        float av[8] = {v0.x, v0.y, v0.z, v0.w, v1.x, v1.y, v1.z, v1.w};
        float e0 = 0, e1 = 0, e2 = 0, e3 = 0;
        #pragma unroll
        for (int d2i = 0; d2i < 8; ++d2i){
          e0 = fmaf(av[d2i], s_wev[d2i * 4 + 0], e0);
          e1 = fmaf(av[d2i], s_wev[d2i * 4 + 1], e1);
          e2 = fmaf(av[d2i], s_wev[d2i * 4 + 2], e2);
          e3 = fmaf(av[d2i], s_wev[d2i * 4 + 3], e3);
        }
        a0 += e0; a1 += e1; a2 += e2; a3 += e3;
        es0 += e0; es1 += e1; es2 += e2; es3 += e3;
      }
      w.x = expf(lrelu(a0)); w.y = expf(lrelu(a1));
      w.z = expf(lrelu(a2)); w.w = expf(lrelu(a3));
    }
    d0 += w.x; d1 += w.y; d2 += w.z; d3 += w.w;
    s_w[wv][lane] = w;
    s_src[wv][lane] = s;
    WAVE_FENCE();
    int nvalid = min(deg - base, 64);
    int nit = (nvalid + 7) >> 3;
    const float* s_wf = (const float*)&s_w[wv][0];
    for (int i = 0; i < nit; ++i){
      int slot = i * 8 + sg;
      int s2 = s_src[wv][slot];
      float wgt = s_wf[slot * 4 + h];
      float4 xv = ((const float4*)xh)[(size_t)s2 * 8 + q];
      acc.x = fmaf(wgt, xv.x, acc.x); acc.y = fmaf(wgt, xv.y, acc.y);
      acc.z = fmaf(wgt, xv.z, acc.z); acc.w = fmaf(wgt, xv.w, acc.w);
    }
    WAVE_FENCE();
  }

  // combine the 8 slot-group partial accumulators
  #pragma unroll
  for (int off = 8; off < 64; off <<= 1){
    acc.x += __shfl_xor(acc.x, off, 64); acc.y += __shfl_xor(acc.y, off, 64);
    acc.z += __shfl_xor(acc.z, off, 64); acc.w += __shfl_xor(acc.w, off, 64);
  }
  #pragma unroll
  for (int off = 1; off < 64; off <<= 1){
    d0 += __shfl_xor(d0, off, 64); d1 += __shfl_xor(d1, off, 64);
    d2 += __shfl_xor(d2, off, 64); d3 += __shfl_xor(d3, off, 64);
  }
  float se0 = 0, se1 = 0, se2 = 0, se3 = 0;
  if constexpr (EMODE != 0){
    #pragma unroll
    for (int off = 1; off < 64; off <<= 1){
      es0 += __shfl_xor(es0, off, 64); es1 += __shfl_xor(es1, off, 64);
      es2 += __shfl_xor(es2, off, 64); es3 += __shfl_xor(es3, off, 64);
    }
    float inv = 1.f / fmaxf((float)deg, 1.f);
    se0 = es0 * inv; se1 = es1 * inv; se2 = es2 * inv; se3 = es3 * inv;
  }
  float4 ssn = ((const float4*)sS)[node];
  float ws0 = expf(lrelu(ssn.x + sd4.x + se0));
  float ws1 = expf(lrelu(ssn.y + sd4.y + se1));
  float ws2 = expf(lrelu(ssn.z + sd4.z + se2));
  float ws3 = expf(lrelu(ssn.w + sd4.w + se3));
  d0 += ws0; d1 += ws1; d2 += ws2; d3 += ws3;
  float wsel = (h == 0) ? ws0 : (h == 1) ? ws1 : (h == 2) ? ws2 : ws3;
  float4 xvn = ((const float4*)xh)[(size_t)node * 8 + q];
  acc.x = fmaf(wsel, xvn.x, acc.x); acc.y = fmaf(wsel, xvn.y, acc.y);
  acc.z = fmaf(wsel, xvn.z, acc.z); acc.w = fmaf(wsel, xvn.w, acc.w);
  float dsel = (h == 0) ? d0 : (h == 1) ? d1 : (h == 2) ? d2 : d3;
  float rin = 1.f / (dsel + 1e-16f);
  float4 val = {acc.x * rin, acc.y * rin, acc.z * rin, acc.w * rin};

  if constexpr (MODE == 0){
    float4 b4 = ((const float4*)bias)[q];
    val.x = elu1(val.x + b4.x); val.y = elu1(val.y + b4.y);
    val.z = elu1(val.z + b4.z); val.w = elu1(val.w + b4.w);
    if (lane < 8) ((float4*)out)[(size_t)node * 8 + lane] = val;
  } else {
    val.x += __shfl_xor(val.x, 2, 64); val.y += __shfl_xor(val.y, 2, 64);
    val.z += __shfl_xor(val.z, 2, 64); val.w += __shfl_xor(val.w, 2, 64);
    val.x += __shfl_xor(val.x, 4, 64); val.y += __shfl_xor(val.y, 4, 64);
    val.z += __shfl_xor(val.z, 4, 64); val.w += __shfl_xor(val.w, 4, 64);
    float4 b4 = ((const float4*)bias)[q & 1];
    val.x = elu1(val.x * 0.25f + b4.x); val.y = elu1(val.y * 0.25f + b4.y);
    val.z = elu1(val.z * 0.25f + b4.z); val.w = elu1(val.w * 0.25f + b4.w);
    if (lane < 2) ((float4*)out)[(size_t)node * 2 + lane] = val;
  }
  }
}

// ---------------- launcher ----------------

extern "C" void kernel_launch(void* const* d_in, const int* in_sizes, int n_in,
                              void* d_out, int out_size, void* d_ws, size_t ws_size,
                              hipStream_t stream){
  const float* x     = (const float*)d_in[0];
  const float* eattr = (const float*)d_in[1];
  const int*   ei    = (const int*)d_in[2];
  const float* W1  = (const float*)d_in[3];
  const float* as1 = (const float*)d_in[4];
  const float* ad1 = (const float*)d_in[5];
  const float* We1 = (const float*)d_in[6];
  const float* ae1 = (const float*)d_in[7];
  const float* b1  = (const float*)d_in[8];
  const float* W2  = (const float*)d_in[9];
  const float* as2 = (const float*)d_in[10];
  const float* ad2 = (const float*)d_in[11];
  const float* b2  = (const float*)d_in[12];
  const float* W3  = (const float*)d_in[13];
  const float* as3 = (const float*)d_in[14];
  const float* ad3 = (const float*)d_in[15];
  const float* b3  = (const float*)d_in[16];

  const int N = in_sizes[0] / 128;
  const int E = in_sizes[2] / 2;
  const int nb_buckets = (N + (1 << W_SHIFT) - 1) >> W_SHIFT;

  const size_t floats_bytes = (size_t)N * 320;                    // xh,sS,sD,h1,h2
  const size_t staged_bytes = (size_t)E * 24;                     // meta 8B + esc 16B
  const size_t int_bytes = ((size_t)N + NBMAX + 256 + (N + 1) + (NBMAX + 1) + NBMAX) * 4;
  const size_t SA = staged_bytes > floats_bytes ? staged_bytes : floats_bytes;
  const size_t need_fast = SA + (size_t)E * 16 /*esc_perm*/ + (size_t)E * 8 /*recs*/
                         + int_bytes + 256;
  const bool fast = ws_size >= need_fast;

  char* b0 = (char*)d_ws;
  float *xh, *sS, *sD, *h1, *h2, *wev;
  int2 *staged_meta, *recs;
  float4 *staged_esc, *esc_perm;
  int *ip;
  if (fast){
    staged_meta = (int2*)b0;
    staged_esc  = (float4*)(b0 + (size_t)E * 8);
    float* fp = (float*)b0;                        // aliases staged; used after CSR build
    xh = fp; fp += (size_t)N * 32;
    sS = fp; fp += (size_t)N * 4;
    sD = fp; fp += (size_t)N * 4;
    h1 = fp; fp += (size_t)N * 32;
    h2 = fp; fp += (size_t)N * 8;
    esc_perm = (float4*)(b0 + SA);
    recs = (int2*)(b0 + SA + (size_t)E * 16);
    ip = (int*)(b0 + SA + (size_t)E * 24);
  } else {
    float* fp = (float*)b0;
    xh = fp; fp += (size_t)N * 32;
    sS = fp; fp += (size_t)N * 4;
    sD = fp; fp += (size_t)N * 4;
    h1 = fp; fp += (size_t)N * 32;
    h2 = fp; fp += (size_t)N * 8;
    staged_meta = (int2*)b0;                       // aliases floats (25.6MB <= 32MB)
    staged_esc = nullptr;
    esc_perm = nullptr;
    recs = (int2*)fp;
    ip = (int*)(recs + (size_t)E);
  }
  int* cnt       = ip; ip += N;
  int* bcnt      = ip; ip += NBMAX;
  int* partials  = ip; ip += 256;
  int* row_start = ip; ip += N + 1;
  int* bstart    = ip; ip += NBMAX + 1;
  int* bcursor   = ip; ip += NBMAX;
  wev = (float*)ip;

  const int B = 256;
  const int nb_scan = cdiv(N, SCAN_B);

  // ---- CSR build ----
  hipMemsetAsync(cnt, 0, (size_t)(N + NBMAX) * sizeof(int), stream);
  wevec_kernel<<<1, 32, 0, stream>>>(We1, ae1, wev);
  hist2_kernel<<<512, B, 0, stream>>>(ei, E, cnt, bcnt);
  scan_partial_kernel<<<nb_scan, SCAN_B, 0, stream>>>(cnt, row_start, partials, N);
  scan_tops_kernel<<<1, 256, 0, stream>>>(partials, nb_scan, row_start, N, E);
  scan_add_kernel<<<cdiv(N, B), B, 0, stream>>>(partials, row_start, N);
  scan_buckets_kernel<<<1, 1024, 0, stream>>>(bcnt, nb_buckets, E, bstart, bcursor);
  if (fast){
    multisplit_esc_kernel<<<cdiv(E, S3_CHUNK), B, 0, stream>>>(ei, E, eattr, wev, bcursor,
                                                               staged_meta, staged_esc);
    bucket_scatter_esc_kernel<<<nb_buckets, B, 0, stream>>>(bstart, staged_meta, staged_esc,
                                                            row_start, N, recs, esc_perm);
  } else {
    multisplit_kernel<<<cdiv(E, S3_CHUNK), B, 0, stream>>>(ei, E, bcursor, staged_meta);
    bucket_scatter_kernel<<<nb_buckets, B, 0, stream>>>(bstart, staged_meta, row_start, N, recs);
  }

  // ---- layer 1: 128 -> 4x8, concat, edge scores ----
  gemm_score_kernel<128,32,8><<<cdiv(N, 8), B, 0, stream>>>(x, W1, as1, ad1, xh, sS, sD, N);
  if (fast)
    gather_kernel<8,0,1><<<cdiv(N, 4), B, 0, stream>>>(row_start, recs, eattr, esc_perm, wev, sS, sD, xh, b1, h1, N);
  else
    gather_kernel<8,0,2><<<cdiv(N, 4), B, 0, stream>>>(row_start, recs, eattr, esc_perm, wev, sS, sD, xh, b1, h1, N);

  // ---- layer 2: 32 -> 4x8, mean heads ----
  gemm_score_kernel<32,32,8><<<cdiv(N, 8), B, 0, stream>>>(h1, W2, as2, ad2, xh, sS, sD, N);
  gather_kernel<8,1,0><<<cdiv(N, 4), B, 0, stream>>>(row_start, recs, eattr, esc_perm, wev, sS, sD, xh, b2, h2, N);

  // ---- layer 3: 8 -> 4x1, mean heads ----
  gemm_score_kernel<8,4,1><<<cdiv(N, 64), B, 0, stream>>>(h2, W3, as3, ad3, xh, sS, sD, N);
  gather_kernel<1,2,0><<<cdiv(N, 4), B, 0, stream>>>(row_start, recs, eattr, esc_perm, wev, sS, sD, xh, b3, (float*)d_out, N);
}

// Round 7
// 528.525 us; speedup vs baseline: 1.4251x; 1.4251x over previous
//
#include <hip/hip_runtime.h>
#include <hip/hip_fp16.h>
#include <cmath>

static inline int cdiv(long a, int b){ return (int)((a + b - 1) / b); }

__device__ __forceinline__ float lrelu(float x){ return x > 0.f ? x : 0.2f * x; }
__device__ __forceinline__ float elu1(float x){ return x > 0.f ? x : expm1f(x); }

// compiler-level fence: keep LDS writes (phase1) before LDS reads (phase2)
// within the same wave; HW DS pipe is in-order per wave.
#define WAVE_FENCE() do { asm volatile("" ::: "memory"); __builtin_amdgcn_sched_barrier(0); } while(0)

#define W_SHIFT 7                 // 128 nodes per bucket
#define BUCKET_N (1 << W_SHIFT)
#define NBMAX   1024              // >= number of buckets (782)
#define S3_CHUNK 4096

// ---------------- CSR build ----------------

// bucket histogram only (no per-node atomics)
__global__ void hist_buckets_kernel(const int* __restrict__ ei, int E, int* __restrict__ bcnt){
  __shared__ int s_b[NBMAX];
  for (int i = threadIdx.x; i < NBMAX; i += blockDim.x) s_b[i] = 0;
  __syncthreads();
  int stride = gridDim.x * blockDim.x;
  for (int e = blockIdx.x * blockDim.x + threadIdx.x; e < E; e += stride)
    atomicAdd(&s_b[ei[E + e] >> W_SHIFT], 1);
  __syncthreads();
  for (int i = threadIdx.x; i < NBMAX; i += blockDim.x)
    if (s_b[i]) atomicAdd(&bcnt[i], s_b[i]);
}

// single-block exclusive scan of bucket counts -> bstart, bcursor
__global__ void scan_buckets_kernel(const int* __restrict__ bcnt, int nb, int total,
                                    int* __restrict__ bstart, int* __restrict__ bcursor){
  __shared__ int s[1024];
  int t = threadIdx.x;
  int v = (t < nb) ? bcnt[t] : 0;
  s[t] = v; __syncthreads();
  #pragma unroll
  for (int off = 1; off < 1024; off <<= 1){
    int u = (t >= off) ? s[t - off] : 0;
    __syncthreads();
    s[t] += u;
    __syncthreads();
  }
  if (t < nb){ bstart[t] = s[t] - v; bcursor[t] = s[t] - v; }
  if (t == 0) bstart[nb] = total;
}

// wev[d*4+h] = sum_c We1[d, h*8+c] * a_e1[h,c]
__global__ void wevec_kernel(const float* __restrict__ We, const float* __restrict__ ae,
                             float* __restrict__ wev){
  int i = threadIdx.x;
  if (i >= 32) return;
  int d = i >> 2, h = i & 3;
  float acc = 0.f;
  #pragma unroll
  for (int c = 0; c < 8; ++c) acc = fmaf(We[d * 32 + h * 8 + c], ae[h * 8 + c], acc);
  wev[d * 4 + h] = acc;
}

// multisplit: stream ei + eattr sequentially, compute esc (fp16x4), stage one
// 16B record {src, dst_local, esc01, esc23} into bucket-contiguous regions.
__global__ void multisplit_kernel(const int* __restrict__ ei, int E,
                                  const float* __restrict__ eattr, const float* __restrict__ wev,
                                  int* __restrict__ bcursor, int4* __restrict__ staged){
  __shared__ int s_hist[NBMAX];
  __shared__ int s_base[NBMAX];
  __shared__ float s_wev[32];
  int t = threadIdx.x;
  if (t < 32) s_wev[t] = wev[t];
  for (int i = t; i < NBMAX; i += 256) s_hist[i] = 0;
  __syncthreads();
  int lo = blockIdx.x * S3_CHUNK;
  int hi = min(lo + S3_CHUNK, E);
  for (int e = lo + t; e < hi; e += 256)
    atomicAdd(&s_hist[ei[E + e] >> W_SHIFT], 1);
  __syncthreads();
  for (int i = t; i < NBMAX; i += 256){
    int c = s_hist[i];
    s_base[i] = c ? atomicAdd(&bcursor[i], c) : 0;
    s_hist[i] = 0;
  }
  __syncthreads();
  for (int e = lo + t; e < hi; e += 256){
    int d = ei[E + e];
    int b = d >> W_SHIFT;
    int pos = s_base[b] + atomicAdd(&s_hist[b], 1);
    const float4* ea = (const float4*)(eattr + (size_t)e * 8);
    float4 v0 = ea[0], v1 = ea[1];
    float av[8] = {v0.x, v0.y, v0.z, v0.w, v1.x, v1.y, v1.z, v1.w};
    float e0 = 0, e1 = 0, e2 = 0, e3 = 0;
    #pragma unroll
    for (int k = 0; k < 8; ++k){
      e0 = fmaf(av[k], s_wev[k * 4 + 0], e0);
      e1 = fmaf(av[k], s_wev[k * 4 + 1], e1);
      e2 = fmaf(av[k], s_wev[k * 4 + 2], e2);
      e3 = fmaf(av[k], s_wev[k * 4 + 3], e3);
    }
    __half2 h01 = __floats2half2_rn(e0, e1);
    __half2 h23 = __floats2half2_rn(e2, e3);
    staged[pos] = make_int4(ei[e], d & (BUCKET_N - 1),
                            __builtin_bit_cast(int, h01), __builtin_bit_cast(int, h23));
  }
}

// per-bucket: build row_start from LDS histogram+scan, then scatter to final
// CSR arrays (srcs 4B, escp 8B) inside an L2-resident window.
__global__ void bucket_scatter_kernel(const int* __restrict__ bstart, const int4* __restrict__ staged,
                                      int n, int* __restrict__ row_start,
                                      int* __restrict__ srcs, uint2* __restrict__ escp){
  __shared__ int s_cnt[BUCKET_N];
  __shared__ int s_cur[BUCKET_N];
  int b = blockIdx.x, t = threadIdx.x;
  int node0 = b << W_SHIFT;
  if (t < BUCKET_N) s_cnt[t] = 0;
  __syncthreads();
  int lo = bstart[b], hi = bstart[b + 1];
  for (int i = lo + t; i < hi; i += 256)
    atomicAdd(&s_cnt[staged[i].y], 1);
  __syncthreads();
  if (t < BUCKET_N) s_cur[t] = s_cnt[t];
  __syncthreads();
  #pragma unroll
  for (int off = 1; off < BUCKET_N; off <<= 1){
    int v = (t < BUCKET_N && t >= off) ? s_cur[t - off] : 0;
    __syncthreads();
    if (t < BUCKET_N) s_cur[t] += v;
    __syncthreads();
  }
  if (t < BUCKET_N){
    int excl = s_cur[t] - s_cnt[t];
    int nd = node0 + t;
    if (nd <= n) row_start[nd] = lo + excl;   // nd==n covered by last bucket
    s_cur[t] = lo + excl;
  }
  __syncthreads();
  for (int i = lo + t; i < hi; i += 256){
    int4 r = staged[i];
    int pos = atomicAdd(&s_cur[r.y], 1);
    srcs[pos] = r.x;
    escp[pos] = make_uint2((unsigned)r.z, (unsigned)r.w);
  }
}

// ---------------- fused node transform + attention pre-scores ----------------
template<int K, int M, int C>
__global__ void gemm_score_kernel(const float* __restrict__ A, const float* __restrict__ W,
                                  const float* __restrict__ asrc, const float* __restrict__ adst,
                                  float* __restrict__ out, float* __restrict__ sS,
                                  float* __restrict__ sD, int n){
  __shared__ float Ws[K * M];
  __shared__ float s_as[M], s_ad[M];
  for (int i = threadIdx.x; i < K * M; i += blockDim.x) Ws[i] = W[i];
  if (threadIdx.x < M){ s_as[threadIdx.x] = asrc[threadIdx.x]; s_ad[threadIdx.x] = adst[threadIdx.x]; }
  __syncthreads();
  constexpr int ROWS = 256 / M;
  int row = blockIdx.x * ROWS + (int)threadIdx.x / M;
  int col = (int)threadIdx.x % M;
  if (row >= n) return;
  const float4* a4 = (const float4*)(A + (size_t)row * K);
  float acc = 0.f;
  #pragma unroll
  for (int k4 = 0; k4 < K / 4; ++k4){
    float4 av = a4[k4];
    acc = fmaf(av.x, Ws[(k4 * 4 + 0) * M + col], acc);
    acc = fmaf(av.y, Ws[(k4 * 4 + 1) * M + col], acc);
    acc = fmaf(av.z, Ws[(k4 * 4 + 2) * M + col], acc);
    acc = fmaf(av.w, Ws[(k4 * 4 + 3) * M + col], acc);
  }
  out[(size_t)row * M + col] = acc;
  float ps = acc * s_as[col], pd = acc * s_ad[col];
  #pragma unroll
  for (int off = 1; off < C; off <<= 1){
    ps += __shfl_xor(ps, off, 64);
    pd += __shfl_xor(pd, off, 64);
  }
  if ((col & (C - 1)) == 0){
    int h = col / C;
    sS[(size_t)row * 4 + h] = ps;
    sD[(size_t)row * 4 + h] = pd;
  }
}

// ---------------- CSR gather-aggregate ----------------
// MODE 0: concat heads + bias + ELU (layer1, OUT=32), EDGE: esc from escp (fp16x4)
// MODE 1: mean heads + bias + ELU   (layer2, OUT=32)
// MODE 2: mean heads + bias         (layer3, OUT=4) — lane-per-edge path
template<int MODE, bool EDGE>
__global__ void gather_kernel(const int* __restrict__ row_start, const int* __restrict__ srcs,
                              const uint2* __restrict__ escp,
                              const float* __restrict__ sS, const float* __restrict__ sD,
                              const float* __restrict__ xh, const float* __restrict__ bias,
                              float* __restrict__ out, int n){
  int wv = threadIdx.x >> 6, lane = threadIdx.x & 63;
  int node = blockIdx.x * 4 + wv;

  if constexpr (MODE == 2){
    if (node >= n) return;
    int rs = row_start[node], deg = row_start[node + 1] - rs;
    float4 sd4 = ((const float4*)sD)[node];
    float4 acc = {0,0,0,0}, dsum = {0,0,0,0};
    for (int k = lane; k < deg; k += 64){
      int s = srcs[rs + k];
      float4 ss = ((const float4*)sS)[s];
      float4 w;
      w.x = expf(lrelu(ss.x + sd4.x)); w.y = expf(lrelu(ss.y + sd4.y));
      w.z = expf(lrelu(ss.z + sd4.z)); w.w = expf(lrelu(ss.w + sd4.w));
      dsum.x += w.x; dsum.y += w.y; dsum.z += w.z; dsum.w += w.w;
      float4 xv = ((const float4*)xh)[s];
      acc.x = fmaf(w.x, xv.x, acc.x); acc.y = fmaf(w.y, xv.y, acc.y);
      acc.z = fmaf(w.z, xv.z, acc.z); acc.w = fmaf(w.w, xv.w, acc.w);
    }
    #pragma unroll
    for (int off = 1; off < 64; off <<= 1){
      acc.x += __shfl_xor(acc.x, off, 64); acc.y += __shfl_xor(acc.y, off, 64);
      acc.z += __shfl_xor(acc.z, off, 64); acc.w += __shfl_xor(acc.w, off, 64);
      dsum.x += __shfl_xor(dsum.x, off, 64); dsum.y += __shfl_xor(dsum.y, off, 64);
      dsum.z += __shfl_xor(dsum.z, off, 64); dsum.w += __shfl_xor(dsum.w, off, 64);
    }
    if (lane == 0){
      float4 ssn = ((const float4*)sS)[node];
      float4 wsf;
      wsf.x = expf(lrelu(ssn.x + sd4.x)); wsf.y = expf(lrelu(ssn.y + sd4.y));
      wsf.z = expf(lrelu(ssn.z + sd4.z)); wsf.w = expf(lrelu(ssn.w + sd4.w));
      float4 xvn = ((const float4*)xh)[node];
      float v = (acc.x + wsf.x * xvn.x) / (dsum.x + wsf.x + 1e-16f)
              + (acc.y + wsf.y * xvn.y) / (dsum.y + wsf.y + 1e-16f)
              + (acc.z + wsf.z * xvn.z) / (dsum.z + wsf.z + 1e-16f)
              + (acc.w + wsf.w * xvn.w) / (dsum.w + wsf.w + 1e-16f);
      out[node] = 0.25f * v + bias[0];
    }
    return;
  } else {
  __shared__ float4 s_w[4][64];
  __shared__ int    s_src[4][64];
  if (node >= n) return;
  int rs = row_start[node], deg = row_start[node + 1] - rs;
  float4 sd4 = ((const float4*)sD)[node];
  int q = lane & 7;          // float4 column of the 32-wide row
  int h = q >> 1;            // head for this column group
  int sg = lane >> 3;        // slot group (8 edges per phase-2 slot set)
  float d0 = 0, d1 = 0, d2 = 0, d3 = 0;
  float es0 = 0, es1 = 0, es2 = 0, es3 = 0;
  float4 acc = {0,0,0,0};

  for (int base = 0; base < deg; base += 64){
    int k = base + lane;
    float4 w = {0,0,0,0}; int s = 0;
    if (k < deg){
      s = srcs[rs + k];
      float4 ss = ((const float4*)sS)[s];
      float a0 = ss.x + sd4.x, a1 = ss.y + sd4.y, a2 = ss.z + sd4.z, a3 = ss.w + sd4.w;
      if constexpr (EDGE){
        uint2 u = escp[rs + k];
        float2 f01 = __half22float2(__builtin_bit_cast(__half2, u.x));
        float2 f23 = __half22float2(__builtin_bit_cast(__half2, u.y));
        a0 += f01.x; a1 += f01.y; a2 += f23.x; a3 += f23.y;
        es0 += f01.x; es1 += f01.y; es2 += f23.x; es3 += f23.y;
      }
      w.x = expf(lrelu(a0)); w.y = expf(lrelu(a1));
      w.z = expf(lrelu(a2)); w.w = expf(lrelu(a3));
    }
    d0 += w.x; d1 += w.y; d2 += w.z; d3 += w.w;
    s_w[wv][lane] = w;
    s_src[wv][lane] = s;
    WAVE_FENCE();
    int nvalid = min(deg - base, 64);
    const float* s_wf = (const float*)&s_w[wv][0];
    // fully-unrolled predicated phase 2: all 8 loads issue independently
    #pragma unroll
    for (int i = 0; i < 8; ++i){
      int slot = i * 8 + sg;
      bool ok = slot < nvalid;
      int s2 = ok ? s_src[wv][slot] : 0;
      float wg = ok ? s_wf[slot * 4 + h] : 0.f;
      float4 xv = ((const float4*)xh)[(size_t)s2 * 8 + q];
      acc.x = fmaf(wg, xv.x, acc.x); acc.y = fmaf(wg, xv.y, acc.y);
      acc.z = fmaf(wg, xv.z, acc.z); acc.w = fmaf(wg, xv.w, acc.w);
    }
    WAVE_FENCE();
  }

  // combine the 8 slot-group partial accumulators
  #pragma unroll
  for (int off = 8; off < 64; off <<= 1){
    acc.x += __shfl_xor(acc.x, off, 64); acc.y += __shfl_xor(acc.y, off, 64);
    acc.z += __shfl_xor(acc.z, off, 64); acc.w += __shfl_xor(acc.w, off, 64);
  }
  #pragma unroll
  for (int off = 1; off < 64; off <<= 1){
    d0 += __shfl_xor(d0, off, 64); d1 += __shfl_xor(d1, off, 64);
    d2 += __shfl_xor(d2, off, 64); d3 += __shfl_xor(d3, off, 64);
  }
  float se0 = 0, se1 = 0, se2 = 0, se3 = 0;
  if constexpr (EDGE){
    #pragma unroll
    for (int off = 1; off < 64; off <<= 1){
      es0 += __shfl_xor(es0, off, 64); es1 += __shfl_xor(es1, off, 64);
      es2 += __shfl_xor(es2, off, 64); es3 += __shfl_xor(es3, off, 64);
    }
    float inv = 1.f / fmaxf((float)deg, 1.f);
    se0 = es0 * inv; se1 = es1 * inv; se2 = es2 * inv; se3 = es3 * inv;
  }
  float4 ssn = ((const float4*)sS)[node];
  float ws0 = expf(lrelu(ssn.x + sd4.x + se0));
  float ws1 = expf(lrelu(ssn.y + sd4.y + se1));
  float ws2 = expf(lrelu(ssn.z + sd4.z + se2));
  float ws3 = expf(lrelu(ssn.w + sd4.w + se3));
  d0 += ws0; d1 += ws1; d2 += ws2; d3 += ws3;
  float wsel = (h == 0) ? ws0 : (h == 1) ? ws1 : (h == 2) ? ws2 : ws3;
  float4 xvn = ((const float4*)xh)[(size_t)node * 8 + q];
  acc.x = fmaf(wsel, xvn.x, acc.x); acc.y = fmaf(wsel, xvn.y, acc.y);
  acc.z = fmaf(wsel, xvn.z, acc.z); acc.w = fmaf(wsel, xvn.w, acc.w);
  float dsel = (h == 0) ? d0 : (h == 1) ? d1 : (h == 2) ? d2 : d3;
  float rin = 1.f / (dsel + 1e-16f);
  float4 val = {acc.x * rin, acc.y * rin, acc.z * rin, acc.w * rin};

  if constexpr (MODE == 0){
    float4 b4 = ((const float4*)bias)[q];
    val.x = elu1(val.x + b4.x); val.y = elu1(val.y + b4.y);
    val.z = elu1(val.z + b4.z); val.w = elu1(val.w + b4.w);
    if (lane < 8) ((float4*)out)[(size_t)node * 8 + lane] = val;
  } else {
    val.x += __shfl_xor(val.x, 2, 64); val.y += __shfl_xor(val.y, 2, 64);
    val.z += __shfl_xor(val.z, 2, 64); val.w += __shfl_xor(val.w, 2, 64);
    val.x += __shfl_xor(val.x, 4, 64); val.y += __shfl_xor(val.y, 4, 64);
    val.z += __shfl_xor(val.z, 4, 64); val.w += __shfl_xor(val.w, 4, 64);
    float4 b4 = ((const float4*)bias)[q & 1];
    val.x = elu1(val.x * 0.25f + b4.x); val.y = elu1(val.y * 0.25f + b4.y);
    val.z = elu1(val.z * 0.25f + b4.z); val.w = elu1(val.w * 0.25f + b4.w);
    if (lane < 2) ((float4*)out)[(size_t)node * 2 + lane] = val;
  }
  }
}

// ---------------- launcher ----------------

extern "C" void kernel_launch(void* const* d_in, const int* in_sizes, int n_in,
                              void* d_out, int out_size, void* d_ws, size_t ws_size,
                              hipStream_t stream){
  const float* x     = (const float*)d_in[0];
  const float* eattr = (const float*)d_in[1];
  const int*   ei    = (const int*)d_in[2];
  const float* W1  = (const float*)d_in[3];
  const float* as1 = (const float*)d_in[4];
  const float* ad1 = (const float*)d_in[5];
  const float* We1 = (const float*)d_in[6];
  const float* ae1 = (const float*)d_in[7];
  const float* b1  = (const float*)d_in[8];
  const float* W2  = (const float*)d_in[9];
  const float* as2 = (const float*)d_in[10];
  const float* ad2 = (const float*)d_in[11];
  const float* b2  = (const float*)d_in[12];
  const float* W3  = (const float*)d_in[13];
  const float* as3 = (const float*)d_in[14];
  const float* ad3 = (const float*)d_in[15];
  const float* b3  = (const float*)d_in[16];

  const int N = in_sizes[0] / 128;
  const int E = in_sizes[2] / 2;
  const int nb_buckets = (N + BUCKET_N - 1) >> W_SHIFT;   // 782 for N=100000

  // layout: [staged int4 E*16 | escp E*8 | srcs E*4 | ints | wev]
  // floats (xh,sS,sD,h1,h2 = N*320 B = 32.3 MB) alias the staged region
  // (E*16 = 51.2 MB); staged is dead before the first gemm writes xh.
  char* b0 = (char*)d_ws;
  int4* staged = (int4*)b0;
  float* fp = (float*)b0;
  float* xh = fp; fp += (size_t)N * 32;
  float* sS = fp; fp += (size_t)N * 4;
  float* sD = fp; fp += (size_t)N * 4;
  float* h1 = fp; fp += (size_t)N * 32;
  float* h2 = fp; fp += (size_t)N * 8;
  uint2* escp = (uint2*)(b0 + (size_t)E * 16);
  int*   srcs = (int*)(b0 + (size_t)E * 24);
  int* ip = (int*)(b0 + (size_t)E * 28);
  int* bcnt      = ip; ip += NBMAX;
  int* bstart    = ip; ip += NBMAX + 1;
  int* bcursor   = ip; ip += NBMAX;
  int* row_start = ip; ip += N + 1;
  float* wev = (float*)ip;

  const int B = 256;

  // ---- CSR build ----
  hipMemsetAsync(bcnt, 0, (size_t)NBMAX * sizeof(int), stream);
  wevec_kernel<<<1, 32, 0, stream>>>(We1, ae1, wev);
  hist_buckets_kernel<<<512, B, 0, stream>>>(ei, E, bcnt);
  scan_buckets_kernel<<<1, 1024, 0, stream>>>(bcnt, nb_buckets, E, bstart, bcursor);
  multisplit_kernel<<<cdiv(E, S3_CHUNK), B, 0, stream>>>(ei, E, eattr, wev, bcursor, staged);
  bucket_scatter_kernel<<<nb_buckets, B, 0, stream>>>(bstart, staged, N, row_start, srcs, escp);

  // ---- layer 1: 128 -> 4x8, concat, edge scores ----
  gemm_score_kernel<128,32,8><<<cdiv(N, 8), B, 0, stream>>>(x, W1, as1, ad1, xh, sS, sD, N);
  gather_kernel<0,true><<<cdiv(N, 4), B, 0, stream>>>(row_start, srcs, escp, sS, sD, xh, b1, h1, N);

  // ---- layer 2: 32 -> 4x8, mean heads ----
  gemm_score_kernel<32,32,8><<<cdiv(N, 8), B, 0, stream>>>(h1, W2, as2, ad2, xh, sS, sD, N);
  gather_kernel<1,false><<<cdiv(N, 4), B, 0, stream>>>(row_start, srcs, escp, sS, sD, xh, b2, h2, N);

  // ---- layer 3: 8 -> 4x1, mean heads ----
  gemm_score_kernel<8,4,1><<<cdiv(N, 64), B, 0, stream>>>(h2, W3, as3, ad3, xh, sS, sD, N);
  gather_kernel<2,false><<<cdiv(N, 4), B, 0, stream>>>(row_start, srcs, escp, sS, sD, xh, b3, (float*)d_out, N);
}

// Round 8
// 483.072 us; speedup vs baseline: 1.5592x; 1.0941x over previous
//
#include <hip/hip_runtime.h>
#include <hip/hip_fp16.h>
#include <cmath>

static inline int cdiv(long a, int b){ return (int)((a + b - 1) / b); }

__device__ __forceinline__ float lrelu(float x){ return x > 0.f ? x : 0.2f * x; }
__device__ __forceinline__ float elu1(float x){ return x > 0.f ? x : expm1f(x); }

// compiler-level fence: keep LDS writes (phase1) before LDS reads (phase2)
// within the same wave; HW DS pipe is in-order per wave.
#define WAVE_FENCE() do { asm volatile("" ::: "memory"); __builtin_amdgcn_sched_barrier(0); } while(0)

#define W_SHIFT 7                 // 128 nodes per bucket
#define BUCKET_N (1 << W_SHIFT)
#define NBMAX   1024              // >= number of buckets (782)
#define S3_CHUNK 8192
#define S3_THREADS 1024

// record: {src, dst_local, esc01(fp16x2), esc23(fp16x2)} — used for staged AND final CSR
// ---------------- CSR build ----------------

__global__ void hist_buckets_kernel(const int* __restrict__ ei, int E, int* __restrict__ bcnt){
  __shared__ int s_b[NBMAX];
  for (int i = threadIdx.x; i < NBMAX; i += blockDim.x) s_b[i] = 0;
  __syncthreads();
  int stride = gridDim.x * blockDim.x;
  for (int e = blockIdx.x * blockDim.x + threadIdx.x; e < E; e += stride)
    atomicAdd(&s_b[ei[E + e] >> W_SHIFT], 1);
  __syncthreads();
  for (int i = threadIdx.x; i < NBMAX; i += blockDim.x)
    if (s_b[i]) atomicAdd(&bcnt[i], s_b[i]);
}

// single-block exclusive scan of bucket counts -> bstart, bcursor; row_start[N]=E
__global__ void scan_buckets_kernel(const int* __restrict__ bcnt, int nb, int total,
                                    int* __restrict__ bstart, int* __restrict__ bcursor,
                                    int* __restrict__ row_start, int n){
  __shared__ int s[1024];
  int t = threadIdx.x;
  int v = (t < nb) ? bcnt[t] : 0;
  s[t] = v; __syncthreads();
  #pragma unroll
  for (int off = 1; off < 1024; off <<= 1){
    int u = (t >= off) ? s[t - off] : 0;
    __syncthreads();
    s[t] += u;
    __syncthreads();
  }
  if (t < nb){ bstart[t] = s[t] - v; bcursor[t] = s[t] - v; }
  if (t == 0){ bstart[nb] = total; row_start[n] = total; }
}

// wev[d*4+h] = sum_c We1[d, h*8+c] * a_e1[h,c]
__global__ void wevec_kernel(const float* __restrict__ We, const float* __restrict__ ae,
                             float* __restrict__ wev){
  int i = threadIdx.x;
  if (i >= 32) return;
  int d = i >> 2, h = i & 3;
  float acc = 0.f;
  #pragma unroll
  for (int c = 0; c < 8; ++c) acc = fmaf(We[d * 32 + h * 8 + c], ae[h * 8 + c], acc);
  wev[d * 4 + h] = acc;
}

// multisplit: stream ei + eattr sequentially, compute esc (fp16x4), stage one
// 16B record into bucket-contiguous regions. 1024 threads for latency hiding.
__global__ __launch_bounds__(S3_THREADS)
void multisplit_kernel(const int* __restrict__ ei, int E,
                       const float* __restrict__ eattr, const float* __restrict__ wev,
                       int* __restrict__ bcursor, int4* __restrict__ staged){
  __shared__ int s_hist[NBMAX];
  __shared__ int s_base[NBMAX];
  __shared__ float s_wev[32];
  int t = threadIdx.x;
  if (t < 32) s_wev[t] = wev[t];
  for (int i = t; i < NBMAX; i += S3_THREADS) s_hist[i] = 0;
  __syncthreads();
  int lo = blockIdx.x * S3_CHUNK;
  int hi = min(lo + S3_CHUNK, E);
  for (int e = lo + t; e < hi; e += S3_THREADS)
    atomicAdd(&s_hist[ei[E + e] >> W_SHIFT], 1);
  __syncthreads();
  for (int i = t; i < NBMAX; i += S3_THREADS){
    int c = s_hist[i];
    s_base[i] = c ? atomicAdd(&bcursor[i], c) : 0;
    s_hist[i] = 0;
  }
  __syncthreads();
  for (int e = lo + t; e < hi; e += S3_THREADS){
    int d = ei[E + e];
    int b = d >> W_SHIFT;
    const float4* ea = (const float4*)(eattr + (size_t)e * 8);
    float4 v0 = ea[0], v1 = ea[1];
    float av[8] = {v0.x, v0.y, v0.z, v0.w, v1.x, v1.y, v1.z, v1.w};
    float e0 = 0, e1 = 0, e2 = 0, e3 = 0;
    #pragma unroll
    for (int k = 0; k < 8; ++k){
      e0 = fmaf(av[k], s_wev[k * 4 + 0], e0);
      e1 = fmaf(av[k], s_wev[k * 4 + 1], e1);
      e2 = fmaf(av[k], s_wev[k * 4 + 2], e2);
      e3 = fmaf(av[k], s_wev[k * 4 + 3], e3);
    }
    __half2 h01 = __floats2half2_rn(e0, e1);
    __half2 h23 = __floats2half2_rn(e2, e3);
    int pos = s_base[b] + atomicAdd(&s_hist[b], 1);
    staged[pos] = make_int4(ei[e], d & (BUCKET_N - 1),
                            __builtin_bit_cast(int, h01), __builtin_bit_cast(int, h23));
  }
}

// per-bucket: build row_start via LDS histogram+scan, then permute staged
// records to final CSR order (one 16B store per edge, L2-resident window).
__global__ __launch_bounds__(S3_THREADS)
void bucket_scatter_kernel(const int* __restrict__ bstart, const int4* __restrict__ staged,
                           int n, int* __restrict__ row_start, int4* __restrict__ recs){
  __shared__ int s_cnt[BUCKET_N];
  __shared__ int s_cur[BUCKET_N];
  int b = blockIdx.x, t = threadIdx.x;
  int node0 = b << W_SHIFT;
  if (t < BUCKET_N) s_cnt[t] = 0;
  __syncthreads();
  int lo = bstart[b], hi = bstart[b + 1];
  for (int i = lo + t; i < hi; i += S3_THREADS)
    atomicAdd(&s_cnt[staged[i].y], 1);
  __syncthreads();
  if (t < BUCKET_N) s_cur[t] = s_cnt[t];
  __syncthreads();
  #pragma unroll
  for (int off = 1; off < BUCKET_N; off <<= 1){
    int v = (t < BUCKET_N && t >= off) ? s_cur[t - off] : 0;
    __syncthreads();
    if (t < BUCKET_N) s_cur[t] += v;
    __syncthreads();
  }
  if (t < BUCKET_N){
    int excl = s_cur[t] - s_cnt[t];
    int nd = node0 + t;
    if (nd <= n) row_start[nd] = lo + excl;
    s_cur[t] = lo + excl;
  }
  __syncthreads();
  for (int i = lo + t; i < hi; i += S3_THREADS){
    int4 r = staged[i];
    int pos = atomicAdd(&s_cur[r.y], 1);
    recs[pos] = r;
  }
}

// ---------------- fused node transform + attention pre-scores ----------------
template<int K, int M, int C>
__global__ void gemm_score_kernel(const float* __restrict__ A, const float* __restrict__ W,
                                  const float* __restrict__ asrc, const float* __restrict__ adst,
                                  float* __restrict__ out, float* __restrict__ sS,
                                  float* __restrict__ sD, int n){
  __shared__ float Ws[K * M];
  __shared__ float s_as[M], s_ad[M];
  for (int i = threadIdx.x; i < K * M; i += blockDim.x) Ws[i] = W[i];
  if (threadIdx.x < M){ s_as[threadIdx.x] = asrc[threadIdx.x]; s_ad[threadIdx.x] = adst[threadIdx.x]; }
  __syncthreads();
  constexpr int ROWS = 256 / M;
  int row = blockIdx.x * ROWS + (int)threadIdx.x / M;
  int col = (int)threadIdx.x % M;
  if (row >= n) return;
  const float4* a4 = (const float4*)(A + (size_t)row * K);
  float acc = 0.f;
  #pragma unroll
  for (int k4 = 0; k4 < K / 4; ++k4){
    float4 av = a4[k4];
    acc = fmaf(av.x, Ws[(k4 * 4 + 0) * M + col], acc);
    acc = fmaf(av.y, Ws[(k4 * 4 + 1) * M + col], acc);
    acc = fmaf(av.z, Ws[(k4 * 4 + 2) * M + col], acc);
    acc = fmaf(av.w, Ws[(k4 * 4 + 3) * M + col], acc);
  }
  out[(size_t)row * M + col] = acc;
  float ps = acc * s_as[col], pd = acc * s_ad[col];
  #pragma unroll
  for (int off = 1; off < C; off <<= 1){
    ps += __shfl_xor(ps, off, 64);
    pd += __shfl_xor(pd, off, 64);
  }
  if ((col & (C - 1)) == 0){
    int h = col / C;
    sS[(size_t)row * 4 + h] = ps;
    sD[(size_t)row * 4 + h] = pd;
  }
}

// ---------------- CSR gather-aggregate ----------------
// MODE 0: concat heads + bias + ELU (layer1, OUT=32), EDGE: esc from rec fp16x4
// MODE 1: mean heads + bias + ELU   (layer2, OUT=32)
// MODE 2: mean heads + bias         (layer3, OUT=4) — lane-per-edge path
template<int MODE, bool EDGE>
__global__ void gather_kernel(const int* __restrict__ row_start, const int4* __restrict__ recs,
                              const float* __restrict__ sS, const float* __restrict__ sD,
                              const float* __restrict__ xh, const float* __restrict__ bias,
                              float* __restrict__ out, int n){
  int wv = threadIdx.x >> 6, lane = threadIdx.x & 63;
  int node = blockIdx.x * 4 + wv;

  if constexpr (MODE == 2){
    if (node >= n) return;
    int rs = row_start[node], deg = row_start[node + 1] - rs;
    float4 sd4 = ((const float4*)sD)[node];
    float4 acc = {0,0,0,0}, dsum = {0,0,0,0};
    for (int k = lane; k < deg; k += 64){
      int s = recs[rs + k].x;
      float4 ss = ((const float4*)sS)[s];
      float4 w;
      w.x = expf(lrelu(ss.x + sd4.x)); w.y = expf(lrelu(ss.y + sd4.y));
      w.z = expf(lrelu(ss.z + sd4.z)); w.w = expf(lrelu(ss.w + sd4.w));
      dsum.x += w.x; dsum.y += w.y; dsum.z += w.z; dsum.w += w.w;
      float4 xv = ((const float4*)xh)[s];
      acc.x = fmaf(w.x, xv.x, acc.x); acc.y = fmaf(w.y, xv.y, acc.y);
      acc.z = fmaf(w.z, xv.z, acc.z); acc.w = fmaf(w.w, xv.w, acc.w);
    }
    #pragma unroll
    for (int off = 1; off < 64; off <<= 1){
      acc.x += __shfl_xor(acc.x, off, 64); acc.y += __shfl_xor(acc.y, off, 64);
      acc.z += __shfl_xor(acc.z, off, 64); acc.w += __shfl_xor(acc.w, off, 64);
      dsum.x += __shfl_xor(dsum.x, off, 64); dsum.y += __shfl_xor(dsum.y, off, 64);
      dsum.z += __shfl_xor(dsum.z, off, 64); dsum.w += __shfl_xor(dsum.w, off, 64);
    }
    if (lane == 0){
      float4 ssn = ((const float4*)sS)[node];
      float4 wsf;
      wsf.x = expf(lrelu(ssn.x + sd4.x)); wsf.y = expf(lrelu(ssn.y + sd4.y));
      wsf.z = expf(lrelu(ssn.z + sd4.z)); wsf.w = expf(lrelu(ssn.w + sd4.w));
      float4 xvn = ((const float4*)xh)[node];
      float v = (acc.x + wsf.x * xvn.x) / (dsum.x + wsf.x + 1e-16f)
              + (acc.y + wsf.y * xvn.y) / (dsum.y + wsf.y + 1e-16f)
              + (acc.z + wsf.z * xvn.z) / (dsum.z + wsf.z + 1e-16f)
              + (acc.w + wsf.w * xvn.w) / (dsum.w + wsf.w + 1e-16f);
      out[node] = 0.25f * v + bias[0];
    }
    return;
  } else {
  __shared__ float4 s_w[4][64];
  __shared__ int    s_src[4][64];
  if (node >= n) return;
  int rs = row_start[node], deg = row_start[node + 1] - rs;
  float4 sd4 = ((const float4*)sD)[node];
  int q = lane & 7;          // float4 column of the 32-wide row
  int h = q >> 1;            // head for this column group
  int sg = lane >> 3;        // slot group (8 edges per phase-2 slot set)
  float d0 = 0, d1 = 0, d2 = 0, d3 = 0;
  float es0 = 0, es1 = 0, es2 = 0, es3 = 0;
  float4 acc = {0,0,0,0};

  for (int base = 0; base < deg; base += 64){
    int k = base + lane;
    float4 w = {0,0,0,0}; int s = 0;
    if (k < deg){
      int4 rec = recs[rs + k];
      s = rec.x;
      float4 ss = ((const float4*)sS)[s];
      float a0 = ss.x + sd4.x, a1 = ss.y + sd4.y, a2 = ss.z + sd4.z, a3 = ss.w + sd4.w;
      if constexpr (EDGE){
        float2 f01 = __half22float2(__builtin_bit_cast(__half2, rec.z));
        float2 f23 = __half22float2(__builtin_bit_cast(__half2, rec.w));
        a0 += f01.x; a1 += f01.y; a2 += f23.x; a3 += f23.y;
        es0 += f01.x; es1 += f01.y; es2 += f23.x; es3 += f23.y;
      }
      w.x = expf(lrelu(a0)); w.y = expf(lrelu(a1));
      w.z = expf(lrelu(a2)); w.w = expf(lrelu(a3));
    }
    d0 += w.x; d1 += w.y; d2 += w.z; d3 += w.w;
    s_w[wv][lane] = w;
    s_src[wv][lane] = s;
    WAVE_FENCE();
    int nvalid = min(deg - base, 64);
    const float* s_wf = (const float*)&s_w[wv][0];
    // group-uniform predication: masked slot-groups issue no VMEM
    #pragma unroll
    for (int i = 0; i < 8; ++i){
      int slot = i * 8 + sg;
      if (slot < nvalid){
        int s2 = s_src[wv][slot];
        float wg = s_wf[slot * 4 + h];
        float4 xv = ((const float4*)xh)[(size_t)s2 * 8 + q];
        acc.x = fmaf(wg, xv.x, acc.x); acc.y = fmaf(wg, xv.y, acc.y);
        acc.z = fmaf(wg, xv.z, acc.z); acc.w = fmaf(wg, xv.w, acc.w);
      }
    }
    WAVE_FENCE();
  }

  // combine the 8 slot-group partial accumulators
  #pragma unroll
  for (int off = 8; off < 64; off <<= 1){
    acc.x += __shfl_xor(acc.x, off, 64); acc.y += __shfl_xor(acc.y, off, 64);
    acc.z += __shfl_xor(acc.z, off, 64); acc.w += __shfl_xor(acc.w, off, 64);
  }
  #pragma unroll
  for (int off = 1; off < 64; off <<= 1){
    d0 += __shfl_xor(d0, off, 64); d1 += __shfl_xor(d1, off, 64);
    d2 += __shfl_xor(d2, off, 64); d3 += __shfl_xor(d3, off, 64);
  }
  float se0 = 0, se1 = 0, se2 = 0, se3 = 0;
  if constexpr (EDGE){
    #pragma unroll
    for (int off = 1; off < 64; off <<= 1){
      es0 += __shfl_xor(es0, off, 64); es1 += __shfl_xor(es1, off, 64);
      es2 += __shfl_xor(es2, off, 64); es3 += __shfl_xor(es3, off, 64);
    }
    float inv = 1.f / fmaxf((float)deg, 1.f);
    se0 = es0 * inv; se1 = es1 * inv; se2 = es2 * inv; se3 = es3 * inv;
  }
  float4 ssn = ((const float4*)sS)[node];
  float ws0 = expf(lrelu(ssn.x + sd4.x + se0));
  float ws1 = expf(lrelu(ssn.y + sd4.y + se1));
  float ws2 = expf(lrelu(ssn.z + sd4.z + se2));
  float ws3 = expf(lrelu(ssn.w + sd4.w + se3));
  d0 += ws0; d1 += ws1; d2 += ws2; d3 += ws3;
  float wsel = (h == 0) ? ws0 : (h == 1) ? ws1 : (h == 2) ? ws2 : ws3;
  float4 xvn = ((const float4*)xh)[(size_t)node * 8 + q];
  acc.x = fmaf(wsel, xvn.x, acc.x); acc.y = fmaf(wsel, xvn.y, acc.y);
  acc.z = fmaf(wsel, xvn.z, acc.z); acc.w = fmaf(wsel, xvn.w, acc.w);
  float dsel = (h == 0) ? d0 : (h == 1) ? d1 : (h == 2) ? d2 : d3;
  float rin = 1.f / (dsel + 1e-16f);
  float4 val = {acc.x * rin, acc.y * rin, acc.z * rin, acc.w * rin};

  if constexpr (MODE == 0){
    float4 b4 = ((const float4*)bias)[q];
    val.x = elu1(val.x + b4.x); val.y = elu1(val.y + b4.y);
    val.z = elu1(val.z + b4.z); val.w = elu1(val.w + b4.w);
    if (lane < 8) ((float4*)out)[(size_t)node * 8 + lane] = val;
  } else {
    val.x += __shfl_xor(val.x, 2, 64); val.y += __shfl_xor(val.y, 2, 64);
    val.z += __shfl_xor(val.z, 2, 64); val.w += __shfl_xor(val.w, 2, 64);
    val.x += __shfl_xor(val.x, 4, 64); val.y += __shfl_xor(val.y, 4, 64);
    val.z += __shfl_xor(val.z, 4, 64); val.w += __shfl_xor(val.w, 4, 64);
    float4 b4 = ((const float4*)bias)[q & 1];
    val.x = elu1(val.x * 0.25f + b4.x); val.y = elu1(val.y * 0.25f + b4.y);
    val.z = elu1(val.z * 0.25f + b4.z); val.w = elu1(val.w * 0.25f + b4.w);
    if (lane < 2) ((float4*)out)[(size_t)node * 2 + lane] = val;
  }
  }
}

// ---------------- launcher ----------------

extern "C" void kernel_launch(void* const* d_in, const int* in_sizes, int n_in,
                              void* d_out, int out_size, void* d_ws, size_t ws_size,
                              hipStream_t stream){
  const float* x     = (const float*)d_in[0];
  const float* eattr = (const float*)d_in[1];
  const int*   ei    = (const int*)d_in[2];
  const float* W1  = (const float*)d_in[3];
  const float* as1 = (const float*)d_in[4];
  const float* ad1 = (const float*)d_in[5];
  const float* We1 = (const float*)d_in[6];
  const float* ae1 = (const float*)d_in[7];
  const float* b1  = (const float*)d_in[8];
  const float* W2  = (const float*)d_in[9];
  const float* as2 = (const float*)d_in[10];
  const float* ad2 = (const float*)d_in[11];
  const float* b2  = (const float*)d_in[12];
  const float* W3  = (const float*)d_in[13];
  const float* as3 = (const float*)d_in[14];
  const float* ad3 = (const float*)d_in[15];
  const float* b3  = (const float*)d_in[16];

  const int N = in_sizes[0] / 128;
  const int E = in_sizes[2] / 2;
  const int nb_buckets = (N + BUCKET_N - 1) >> W_SHIFT;   // 782 for N=100000

  // layout: [staged int4 E | recs int4 E | ints | wev]
  // floats (xh,sS,sD,h1,h2 = N*320 B = 32 MB) alias the staged region
  // (E*16 = 51.2 MB); staged is dead before the first gemm writes xh.
  char* b0 = (char*)d_ws;
  int4* staged = (int4*)b0;
  float* fp = (float*)b0;
  float* xh = fp; fp += (size_t)N * 32;
  float* sS = fp; fp += (size_t)N * 4;
  float* sD = fp; fp += (size_t)N * 4;
  float* h1 = fp; fp += (size_t)N * 32;
  float* h2 = fp; fp += (size_t)N * 8;
  int4* recs = (int4*)(b0 + (size_t)E * 16);
  int* ip = (int*)(b0 + (size_t)E * 32);
  int* bcnt      = ip; ip += NBMAX;
  int* bstart    = ip; ip += NBMAX + 1;
  int* bcursor   = ip; ip += NBMAX;
  int* row_start = ip; ip += N + 1;
  float* wev = (float*)ip;

  const int B = 256;

  // ---- CSR build ----
  hipMemsetAsync(bcnt, 0, (size_t)NBMAX * sizeof(int), stream);
  wevec_kernel<<<1, 32, 0, stream>>>(We1, ae1, wev);
  hist_buckets_kernel<<<512, B, 0, stream>>>(ei, E, bcnt);
  scan_buckets_kernel<<<1, 1024, 0, stream>>>(bcnt, nb_buckets, E, bstart, bcursor, row_start, N);
  multisplit_kernel<<<cdiv(E, S3_CHUNK), S3_THREADS, 0, stream>>>(ei, E, eattr, wev, bcursor, staged);
  bucket_scatter_kernel<<<nb_buckets, S3_THREADS, 0, stream>>>(bstart, staged, N, row_start, recs);

  // ---- layer 1: 128 -> 4x8, concat, edge scores ----
  gemm_score_kernel<128,32,8><<<cdiv(N, 8), B, 0, stream>>>(x, W1, as1, ad1, xh, sS, sD, N);
  gather_kernel<0,true><<<cdiv(N, 4), B, 0, stream>>>(row_start, recs, sS, sD, xh, b1, h1, N);

  // ---- layer 2: 32 -> 4x8, mean heads ----
  gemm_score_kernel<32,32,8><<<cdiv(N, 8), B, 0, stream>>>(h1, W2, as2, ad2, xh, sS, sD, N);
  gather_kernel<1,false><<<cdiv(N, 4), B, 0, stream>>>(row_start, recs, sS, sD, xh, b2, h2, N);

  // ---- layer 3: 8 -> 4x1, mean heads ----
  gemm_score_kernel<8,4,1><<<cdiv(N, 64), B, 0, stream>>>(h2, W3, as3, ad3, xh, sS, sD, N);
  gather_kernel<2,false><<<cdiv(N, 4), B, 0, stream>>>(row_start, recs, sS, sD, xh, b3, (float*)d_out, N);
}

// Round 9
// 462.251 us; speedup vs baseline: 1.6295x; 1.0450x over previous
//
#include <hip/hip_runtime.h>
#include <hip/hip_fp16.h>
#include <cmath>

static inline int cdiv(long a, int b){ return (int)((a + b - 1) / b); }

__device__ __forceinline__ float lrelu(float x){ return x > 0.f ? x : 0.2f * x; }
__device__ __forceinline__ float elu1(float x){ return x > 0.f ? x : expm1f(x); }

// compiler-level fence: keep LDS writes (phase1) before LDS reads (phase2)
// within the same wave; HW DS pipe is in-order per wave.
#define WAVE_FENCE() do { asm volatile("" ::: "memory"); __builtin_amdgcn_sched_barrier(0); } while(0)

#define W_SHIFT 7                 // 128 nodes per bucket
#define BUCKET_N (1 << W_SHIFT)
#define NBMAX   1024              // >= number of buckets (782)
#define NCHUNKS 512               // fixed grid: 2 blocks/CU
#define MS_THREADS 1024

// record: {src, dst_local, esc01(fp16x2), esc23(fp16x2)} — staged AND final CSR

// ---------------- CSR build (atomic-free scheduling) ----------------

// per-chunk bucket histogram -> hist2d[chunk][NBMAX]; no global atomics
__global__ __launch_bounds__(MS_THREADS)
void hist_chunks_kernel(const int* __restrict__ ei, int E, int CH, int* __restrict__ hist2d){
  __shared__ int s_b[NBMAX];
  int t = threadIdx.x, chunk = blockIdx.x;
  for (int i = t; i < NBMAX; i += MS_THREADS) s_b[i] = 0;
  __syncthreads();
  int lo = chunk * CH, hi = min(lo + CH, E);
  for (int e = lo + t; e < hi; e += MS_THREADS)
    atomicAdd(&s_b[ei[E + e] >> W_SHIFT], 1);
  __syncthreads();
  int* row = hist2d + (size_t)chunk * NBMAX;
  for (int i = t; i < NBMAX; i += MS_THREADS) row[i] = s_b[i];
}

// per bucket: exclusive prefix over chunks (in place), total -> bcnt
__global__ __launch_bounds__(NCHUNKS)
void col_scan_kernel(int* __restrict__ hist2d, int* __restrict__ bcnt){
  __shared__ int s[NCHUNKS];
  int b = blockIdx.x, t = threadIdx.x;
  int v = hist2d[(size_t)t * NBMAX + b];
  s[t] = v; __syncthreads();
  #pragma unroll
  for (int off = 1; off < NCHUNKS; off <<= 1){
    int u = (t >= off) ? s[t - off] : 0;
    __syncthreads();
    s[t] += u;
    __syncthreads();
  }
  hist2d[(size_t)t * NBMAX + b] = s[t] - v;   // exclusive prefix
  if (t == NCHUNKS - 1) bcnt[b] = s[t];
}

// single-block exclusive scan of bucket totals -> bstart; row_start[N]=E
__global__ void scan_buckets_kernel(const int* __restrict__ bcnt, int nb, int total,
                                    int* __restrict__ bstart, int* __restrict__ row_start, int n){
  __shared__ int s[1024];
  int t = threadIdx.x;
  int v = (t < nb) ? bcnt[t] : 0;
  s[t] = v; __syncthreads();
  #pragma unroll
  for (int off = 1; off < 1024; off <<= 1){
    int u = (t >= off) ? s[t - off] : 0;
    __syncthreads();
    s[t] += u;
    __syncthreads();
  }
  bstart[t] = (t < nb) ? s[t] - v : total;
  if (t == 0){ bstart[NBMAX] = total; row_start[n] = total; }
}

// wev[d*4+h] = sum_c We1[d, h*8+c] * a_e1[h,c]
__global__ void wevec_kernel(const float* __restrict__ We, const float* __restrict__ ae,
                             float* __restrict__ wev){
  int i = threadIdx.x;
  if (i >= 32) return;
  int d = i >> 2, h = i & 3;
  float acc = 0.f;
  #pragma unroll
  for (int c = 0; c < 8; ++c) acc = fmaf(We[d * 32 + h * 8 + c], ae[h * 8 + c], acc);
  wev[d * 4 + h] = acc;
}

// multisplit: deterministic bases (bstart + per-chunk prefix), no global atomics.
// Streams ei + eattr sequentially, computes esc fp16x4, stages one 16B record.
__global__ __launch_bounds__(MS_THREADS)
void multisplit_kernel(const int* __restrict__ ei, int E, int CH,
                       const float* __restrict__ eattr, const float* __restrict__ wev,
                       const int* __restrict__ bstart, const int* __restrict__ prefix2d,
                       int4* __restrict__ staged){
  __shared__ int s_hist[NBMAX];
  __shared__ int s_base[NBMAX];
  __shared__ float s_wev[32];
  int t = threadIdx.x, chunk = blockIdx.x;
  if (t < 32) s_wev[t] = wev[t];
  const int* pre = prefix2d + (size_t)chunk * NBMAX;
  for (int i = t; i < NBMAX; i += MS_THREADS){
    s_base[i] = bstart[i] + pre[i];
    s_hist[i] = 0;
  }
  __syncthreads();
  int lo = chunk * CH, hi = min(lo + CH, E);
  for (int e = lo + t; e < hi; e += MS_THREADS){
    int d = ei[E + e];
    int b = d >> W_SHIFT;
    const float4* ea = (const float4*)(eattr + (size_t)e * 8);
    float4 v0 = ea[0], v1 = ea[1];
    float av[8] = {v0.x, v0.y, v0.z, v0.w, v1.x, v1.y, v1.z, v1.w};
    float e0 = 0, e1 = 0, e2 = 0, e3 = 0;
    #pragma unroll
    for (int k = 0; k < 8; ++k){
      e0 = fmaf(av[k], s_wev[k * 4 + 0], e0);
      e1 = fmaf(av[k], s_wev[k * 4 + 1], e1);
      e2 = fmaf(av[k], s_wev[k * 4 + 2], e2);
      e3 = fmaf(av[k], s_wev[k * 4 + 3], e3);
    }
    __half2 h01 = __floats2half2_rn(e0, e1);
    __half2 h23 = __floats2half2_rn(e2, e3);
    int pos = s_base[b] + atomicAdd(&s_hist[b], 1);
    staged[pos] = make_int4(ei[e], d & (BUCKET_N - 1),
                            __builtin_bit_cast(int, h01), __builtin_bit_cast(int, h23));
  }
}

// per-bucket: build row_start via LDS histogram+scan, then permute staged
// records to final CSR order (one 16B store per edge, L2-resident window).
__global__ __launch_bounds__(MS_THREADS)
void bucket_scatter_kernel(const int* __restrict__ bstart, const int4* __restrict__ staged,
                           int n, int* __restrict__ row_start, int4* __restrict__ recs){
  __shared__ int s_cnt[BUCKET_N];
  __shared__ int s_cur[BUCKET_N];
  int b = blockIdx.x, t = threadIdx.x;
  int node0 = b << W_SHIFT;
  if (t < BUCKET_N) s_cnt[t] = 0;
  __syncthreads();
  int lo = bstart[b], hi = bstart[b + 1];
  for (int i = lo + t; i < hi; i += MS_THREADS)
    atomicAdd(&s_cnt[staged[i].y], 1);
  __syncthreads();
  if (t < BUCKET_N) s_cur[t] = s_cnt[t];
  __syncthreads();
  #pragma unroll
  for (int off = 1; off < BUCKET_N; off <<= 1){
    int v = (t < BUCKET_N && t >= off) ? s_cur[t - off] : 0;
    __syncthreads();
    if (t < BUCKET_N) s_cur[t] += v;
    __syncthreads();
  }
  if (t < BUCKET_N){
    int excl = s_cur[t] - s_cnt[t];
    int nd = node0 + t;
    if (nd <= n) row_start[nd] = lo + excl;
    s_cur[t] = lo + excl;
  }
  __syncthreads();
  for (int i = lo + t; i < hi; i += MS_THREADS){
    int4 r = staged[i];
    int pos = atomicAdd(&s_cur[r.y], 1);
    recs[pos] = r;
  }
}

// ---------------- fused node transform + attention pre-scores ----------------
template<int K, int M, int C>
__global__ void gemm_score_kernel(const float* __restrict__ A, const float* __restrict__ W,
                                  const float* __restrict__ asrc, const float* __restrict__ adst,
                                  float* __restrict__ out, float* __restrict__ sS,
                                  float* __restrict__ sD, int n){
  __shared__ float Ws[K * M];
  __shared__ float s_as[M], s_ad[M];
  for (int i = threadIdx.x; i < K * M; i += blockDim.x) Ws[i] = W[i];
  if (threadIdx.x < M){ s_as[threadIdx.x] = asrc[threadIdx.x]; s_ad[threadIdx.x] = adst[threadIdx.x]; }
  __syncthreads();
  constexpr int ROWS = 256 / M;
  int row = blockIdx.x * ROWS + (int)threadIdx.x / M;
  int col = (int)threadIdx.x % M;
  if (row >= n) return;
  const float4* a4 = (const float4*)(A + (size_t)row * K);
  float acc = 0.f;
  #pragma unroll
  for (int k4 = 0; k4 < K / 4; ++k4){
    float4 av = a4[k4];
    acc = fmaf(av.x, Ws[(k4 * 4 + 0) * M + col], acc);
    acc = fmaf(av.y, Ws[(k4 * 4 + 1) * M + col], acc);
    acc = fmaf(av.z, Ws[(k4 * 4 + 2) * M + col], acc);
    acc = fmaf(av.w, Ws[(k4 * 4 + 3) * M + col], acc);
  }
  out[(size_t)row * M + col] = acc;
  float ps = acc * s_as[col], pd = acc * s_ad[col];
  #pragma unroll
  for (int off = 1; off < C; off <<= 1){
    ps += __shfl_xor(ps, off, 64);
    pd += __shfl_xor(pd, off, 64);
  }
  if ((col & (C - 1)) == 0){
    int h = col / C;
    sS[(size_t)row * 4 + h] = ps;
    sD[(size_t)row * 4 + h] = pd;
  }
}

// ---------------- CSR gather-aggregate ----------------
// MODE 0: concat heads + bias + ELU (layer1, OUT=32), EDGE: esc from rec fp16x4
// MODE 1: mean heads + bias + ELU   (layer2, OUT=32)
// MODE 2: mean heads + bias         (layer3, OUT=4) — lane-per-edge path
template<int MODE, bool EDGE>
__global__ void gather_kernel(const int* __restrict__ row_start, const int4* __restrict__ recs,
                              const float* __restrict__ sS, const float* __restrict__ sD,
                              const float* __restrict__ xh, const float* __restrict__ bias,
                              float* __restrict__ out, int n){
  int wv = threadIdx.x >> 6, lane = threadIdx.x & 63;
  int node = blockIdx.x * 4 + wv;

  if constexpr (MODE == 2){
    if (node >= n) return;
    int rs = row_start[node], deg = row_start[node + 1] - rs;
    float4 sd4 = ((const float4*)sD)[node];
    float4 acc = {0,0,0,0}, dsum = {0,0,0,0};
    for (int k = lane; k < deg; k += 64){
      int s = recs[rs + k].x;
      float4 ss = ((const float4*)sS)[s];
      float4 w;
      w.x = expf(lrelu(ss.x + sd4.x)); w.y = expf(lrelu(ss.y + sd4.y));
      w.z = expf(lrelu(ss.z + sd4.z)); w.w = expf(lrelu(ss.w + sd4.w));
      dsum.x += w.x; dsum.y += w.y; dsum.z += w.z; dsum.w += w.w;
      float4 xv = ((const float4*)xh)[s];
      acc.x = fmaf(w.x, xv.x, acc.x); acc.y = fmaf(w.y, xv.y, acc.y);
      acc.z = fmaf(w.z, xv.z, acc.z); acc.w = fmaf(w.w, xv.w, acc.w);
    }
    #pragma unroll
    for (int off = 1; off < 64; off <<= 1){
      acc.x += __shfl_xor(acc.x, off, 64); acc.y += __shfl_xor(acc.y, off, 64);
      acc.z += __shfl_xor(acc.z, off, 64); acc.w += __shfl_xor(acc.w, off, 64);
      dsum.x += __shfl_xor(dsum.x, off, 64); dsum.y += __shfl_xor(dsum.y, off, 64);
      dsum.z += __shfl_xor(dsum.z, off, 64); dsum.w += __shfl_xor(dsum.w, off, 64);
    }
    if (lane == 0){
      float4 ssn = ((const float4*)sS)[node];
      float4 wsf;
      wsf.x = expf(lrelu(ssn.x + sd4.x)); wsf.y = expf(lrelu(ssn.y + sd4.y));
      wsf.z = expf(lrelu(ssn.z + sd4.z)); wsf.w = expf(lrelu(ssn.w + sd4.w));
      float4 xvn = ((const float4*)xh)[node];
      float v = (acc.x + wsf.x * xvn.x) / (dsum.x + wsf.x + 1e-16f)
              + (acc.y + wsf.y * xvn.y) / (dsum.y + wsf.y + 1e-16f)
              + (acc.z + wsf.z * xvn.z) / (dsum.z + wsf.z + 1e-16f)
              + (acc.w + wsf.w * xvn.w) / (dsum.w + wsf.w + 1e-16f);
      out[node] = 0.25f * v + bias[0];
    }
    return;
  } else {
  __shared__ float4 s_w[4][64];
  __shared__ int    s_src[4][64];
  if (node >= n) return;
  int rs = row_start[node], deg = row_start[node + 1] - rs;
  float4 sd4 = ((const float4*)sD)[node];
  int q = lane & 7;          // float4 column of the 32-wide row
  int h = q >> 1;            // head for this column group
  int sg = lane >> 3;        // slot group (8 edges per phase-2 slot set)
  float d0 = 0, d1 = 0, d2 = 0, d3 = 0;
  float es0 = 0, es1 = 0, es2 = 0, es3 = 0;
  float4 acc = {0,0,0,0};

  for (int base = 0; base < deg; base += 64){
    int k = base + lane;
    float4 w = {0,0,0,0}; int s = 0;
    if (k < deg){
      int4 rec = recs[rs + k];
      s = rec.x;
      float4 ss = ((const float4*)sS)[s];
      float a0 = ss.x + sd4.x, a1 = ss.y + sd4.y, a2 = ss.z + sd4.z, a3 = ss.w + sd4.w;
      if constexpr (EDGE){
        float2 f01 = __half22float2(__builtin_bit_cast(__half2, rec.z));
        float2 f23 = __half22float2(__builtin_bit_cast(__half2, rec.w));
        a0 += f01.x; a1 += f01.y; a2 += f23.x; a3 += f23.y;
        es0 += f01.x; es1 += f01.y; es2 += f23.x; es3 += f23.y;
      }
      w.x = expf(lrelu(a0)); w.y = expf(lrelu(a1));
      w.z = expf(lrelu(a2)); w.w = expf(lrelu(a3));
    }
    d0 += w.x; d1 += w.y; d2 += w.z; d3 += w.w;
    s_w[wv][lane] = w;
    s_src[wv][lane] = s;
    WAVE_FENCE();
    int nvalid = min(deg - base, 64);
    const float* s_wf = (const float*)&s_w[wv][0];
    #pragma unroll
    for (int i = 0; i < 8; ++i){
      int slot = i * 8 + sg;
      if (slot < nvalid){
        int s2 = s_src[wv][slot];
        float wg = s_wf[slot * 4 + h];
        float4 xv = ((const float4*)xh)[(size_t)s2 * 8 + q];
        acc.x = fmaf(wg, xv.x, acc.x); acc.y = fmaf(wg, xv.y, acc.y);
        acc.z = fmaf(wg, xv.z, acc.z); acc.w = fmaf(wg, xv.w, acc.w);
      }
    }
    WAVE_FENCE();
  }

  #pragma unroll
  for (int off = 8; off < 64; off <<= 1){
    acc.x += __shfl_xor(acc.x, off, 64); acc.y += __shfl_xor(acc.y, off, 64);
    acc.z += __shfl_xor(acc.z, off, 64); acc.w += __shfl_xor(acc.w, off, 64);
  }
  #pragma unroll
  for (int off = 1; off < 64; off <<= 1){
    d0 += __shfl_xor(d0, off, 64); d1 += __shfl_xor(d1, off, 64);
    d2 += __shfl_xor(d2, off, 64); d3 += __shfl_xor(d3, off, 64);
  }
  float se0 = 0, se1 = 0, se2 = 0, se3 = 0;
  if constexpr (EDGE){
    #pragma unroll
    for (int off = 1; off < 64; off <<= 1){
      es0 += __shfl_xor(es0, off, 64); es1 += __shfl_xor(es1, off, 64);
      es2 += __shfl_xor(es2, off, 64); es3 += __shfl_xor(es3, off, 64);
    }
    float inv = 1.f / fmaxf((float)deg, 1.f);
    se0 = es0 * inv; se1 = es1 * inv; se2 = es2 * inv; se3 = es3 * inv;
  }
  float4 ssn = ((const float4*)sS)[node];
  float ws0 = expf(lrelu(ssn.x + sd4.x + se0));
  float ws1 = expf(lrelu(ssn.y + sd4.y + se1));
  float ws2 = expf(lrelu(ssn.z + sd4.z + se2));
  float ws3 = expf(lrelu(ssn.w + sd4.w + se3));
  d0 += ws0; d1 += ws1; d2 += ws2; d3 += ws3;
  float wsel = (h == 0) ? ws0 : (h == 1) ? ws1 : (h == 2) ? ws2 : ws3;
  float4 xvn = ((const float4*)xh)[(size_t)node * 8 + q];
  acc.x = fmaf(wsel, xvn.x, acc.x); acc.y = fmaf(wsel, xvn.y, acc.y);
  acc.z = fmaf(wsel, xvn.z, acc.z); acc.w = fmaf(wsel, xvn.w, acc.w);
  float dsel = (h == 0) ? d0 : (h == 1) ? d1 : (h == 2) ? d2 : d3;
  float rin = 1.f / (dsel + 1e-16f);
  float4 val = {acc.x * rin, acc.y * rin, acc.z * rin, acc.w * rin};

  if constexpr (MODE == 0){
    float4 b4 = ((const float4*)bias)[q];
    val.x = elu1(val.x + b4.x); val.y = elu1(val.y + b4.y);
    val.z = elu1(val.z + b4.z); val.w = elu1(val.w + b4.w);
    if (lane < 8) ((float4*)out)[(size_t)node * 8 + lane] = val;
  } else {
    val.x += __shfl_xor(val.x, 2, 64); val.y += __shfl_xor(val.y, 2, 64);
    val.z += __shfl_xor(val.z, 2, 64); val.w += __shfl_xor(val.w, 2, 64);
    val.x += __shfl_xor(val.x, 4, 64); val.y += __shfl_xor(val.y, 4, 64);
    val.z += __shfl_xor(val.z, 4, 64); val.w += __shfl_xor(val.w, 4, 64);
    float4 b4 = ((const float4*)bias)[q & 1];
    val.x = elu1(val.x * 0.25f + b4.x); val.y = elu1(val.y * 0.25f + b4.y);
    val.z = elu1(val.z * 0.25f + b4.z); val.w = elu1(val.w * 0.25f + b4.w);
    if (lane < 2) ((float4*)out)[(size_t)node * 2 + lane] = val;
  }
  }
}

// ---------------- launcher ----------------

extern "C" void kernel_launch(void* const* d_in, const int* in_sizes, int n_in,
                              void* d_out, int out_size, void* d_ws, size_t ws_size,
                              hipStream_t stream){
  const float* x     = (const float*)d_in[0];
  const float* eattr = (const float*)d_in[1];
  const int*   ei    = (const int*)d_in[2];
  const float* W1  = (const float*)d_in[3];
  const float* as1 = (const float*)d_in[4];
  const float* ad1 = (const float*)d_in[5];
  const float* We1 = (const float*)d_in[6];
  const float* ae1 = (const float*)d_in[7];
  const float* b1  = (const float*)d_in[8];
  const float* W2  = (const float*)d_in[9];
  const float* as2 = (const float*)d_in[10];
  const float* ad2 = (const float*)d_in[11];
  const float* b2  = (const float*)d_in[12];
  const float* W3  = (const float*)d_in[13];
  const float* as3 = (const float*)d_in[14];
  const float* ad3 = (const float*)d_in[15];
  const float* b3  = (const float*)d_in[16];

  const int N = in_sizes[0] / 128;
  const int E = in_sizes[2] / 2;
  const int nb_buckets = (N + BUCKET_N - 1) >> W_SHIFT;   // 782 for N=100000
  const int CH = cdiv(E, NCHUNKS);

  // layout: [staged int4 E | recs int4 E | hist2d NCHUNKS*NBMAX | ints | wev]
  // floats (xh,sS,sD,h1,h2 = N*320 B = 32 MB) alias the staged region
  // (E*16 = 51.2 MB); staged is dead before the first gemm writes xh.
  char* b0 = (char*)d_ws;
  int4* staged = (int4*)b0;
  float* fp = (float*)b0;
  float* xh = fp; fp += (size_t)N * 32;
  float* sS = fp; fp += (size_t)N * 4;
  float* sD = fp; fp += (size_t)N * 4;
  float* h1 = fp; fp += (size_t)N * 32;
  float* h2 = fp; fp += (size_t)N * 8;
  int4* recs = (int4*)(b0 + (size_t)E * 16);
  int* hist2d = (int*)(b0 + (size_t)E * 32);
  int* ip = hist2d + (size_t)NCHUNKS * NBMAX;
  int* bcnt      = ip; ip += NBMAX;
  int* bstart    = ip; ip += NBMAX + 1;
  int* row_start = ip; ip += N + 1;
  float* wev = (float*)ip;

  const int B = 256;

  // ---- CSR build: plan (no global atomics) -> multisplit -> bucket scatter ----
  wevec_kernel<<<1, 32, 0, stream>>>(We1, ae1, wev);
  hist_chunks_kernel<<<NCHUNKS, MS_THREADS, 0, stream>>>(ei, E, CH, hist2d);
  col_scan_kernel<<<nb_buckets, NCHUNKS, 0, stream>>>(hist2d, bcnt);
  scan_buckets_kernel<<<1, 1024, 0, stream>>>(bcnt, nb_buckets, E, bstart, row_start, N);
  multisplit_kernel<<<NCHUNKS, MS_THREADS, 0, stream>>>(ei, E, CH, eattr, wev, bstart, hist2d, staged);
  bucket_scatter_kernel<<<nb_buckets, MS_THREADS, 0, stream>>>(bstart, staged, N, row_start, recs);

  // ---- layer 1: 128 -> 4x8, concat, edge scores ----
  gemm_score_kernel<128,32,8><<<cdiv(N, 8), B, 0, stream>>>(x, W1, as1, ad1, xh, sS, sD, N);
  gather_kernel<0,true><<<cdiv(N, 4), B, 0, stream>>>(row_start, recs, sS, sD, xh, b1, h1, N);

  // ---- layer 2: 32 -> 4x8, mean heads ----
  gemm_score_kernel<32,32,8><<<cdiv(N, 8), B, 0, stream>>>(h1, W2, as2, ad2, xh, sS, sD, N);
  gather_kernel<1,false><<<cdiv(N, 4), B, 0, stream>>>(row_start, recs, sS, sD, xh, b2, h2, N);

  // ---- layer 3: 8 -> 4x1, mean heads ----
  gemm_score_kernel<8,4,1><<<cdiv(N, 64), B, 0, stream>>>(h2, W3, as3, ad3, xh, sS, sD, N);
  gather_kernel<2,false><<<cdiv(N, 4), B, 0, stream>>>(row_start, recs, sS, sD, xh, b3, (float*)d_out, N);
}